// Round 5
// baseline (500.227 us; speedup 1.0000x reference)
//
#include <hip/hip_runtime.h>
#include <hip/hip_bf16.h>
#include <math.h>

// Problem dims
#define BB 16
#define NN 100
#define MAXNB 10
#define NBONDS 120
#define AF 82
#define BF 6
#define HH 300
#define BIN 11
#define DEPTH 3
#define KTOP 80

typedef __attribute__((ext_vector_type(8))) short short8;
typedef __attribute__((ext_vector_type(4))) float floatx4;

__device__ __forceinline__ unsigned short f2bf(float f) {
    unsigned int u = __float_as_uint(f);
    unsigned int r = (u + 0x7FFFu + ((u >> 16) & 1u)) >> 16;
    return (unsigned short)r;
}

// ---------------------------------------------------------------------------
// k_gemm300 v2: register-blocked GEMM, C[:, widx*300+col] = act(A@W + bias + Add)
// Block = 320 threads = 80 col-quads x 4 row-groups. Tile: 16 rows x 300 cols.
// ---------------------------------------------------------------------------
__global__ __launch_bounds__(320) void k_gemm300(
    const float* __restrict__ A, int M, int Kd,
    const float* __restrict__ W0, const float* __restrict__ W1,
    const float* __restrict__ W2, const float* __restrict__ W3,
    float* __restrict__ C, int ldc,
    const float* __restrict__ bias,
    const float* __restrict__ Add, int ldAdd, int addOff,
    int act)
{
    __shared__ float sa[16 * 300];               // 19.2 KB max (Kd<=300)
    const int widx = blockIdx.x;
    const float* __restrict__ W =
        (widx == 0) ? W0 : (widx == 1) ? W1 : (widx == 2) ? W2 : W3;
    const int row0 = blockIdx.y * 16;
    const int tid = threadIdx.x;
    const int Kd4 = (Kd + 3) >> 2;
    const int ld  = Kd4 * 4;

    if ((Kd & 3) == 0) {
        const float4* A4 = (const float4*)A;
        float4* sa4 = (float4*)sa;
        const int tot4 = 16 * Kd4;
        for (int idx = tid; idx < tot4; idx += 320) {
            int r = idx / Kd4;
            int q = idx - r * Kd4;
            int row = row0 + r;
            float4 v = make_float4(0.f, 0.f, 0.f, 0.f);
            if (row < M) v = A4[(size_t)row * Kd4 + q];
            sa4[idx] = v;
        }
    } else {
        const int tot = 16 * ld;
        for (int idx = tid; idx < tot; idx += 320) {
            int r = idx / ld;
            int c = idx - r * ld;
            int row = row0 + r;
            float v = 0.f;
            if (row < M && c < Kd) v = A[(size_t)row * Kd + c];
            sa[idx] = v;
        }
    }
    __syncthreads();

    const int quad = tid % 80;
    const int rowg = tid / 80;
    const bool ok = (quad < 75);

    if (ok) {
        const float4* W4 = (const float4*)W;
        const float4* sa4 = (const float4*)sa;
        float4 acc0 = make_float4(0.f,0.f,0.f,0.f);
        float4 acc1 = acc0, acc2 = acc0, acc3 = acc0;
        const int r0 = rowg * 4;
        const int kfull = Kd >> 2;

        for (int kc = 0; kc < kfull; kc++) {
            float4 w0 = W4[(size_t)(kc*4+0) * 75 + quad];
            float4 w1 = W4[(size_t)(kc*4+1) * 75 + quad];
            float4 w2 = W4[(size_t)(kc*4+2) * 75 + quad];
            float4 w3 = W4[(size_t)(kc*4+3) * 75 + quad];
            float4 a0 = sa4[(r0+0) * Kd4 + kc];
            float4 a1 = sa4[(r0+1) * Kd4 + kc];
            float4 a2 = sa4[(r0+2) * Kd4 + kc];
            float4 a3 = sa4[(r0+3) * Kd4 + kc];
#define GSTEP(ACC, AV) \
            ACC.x = fmaf(AV.x, w0.x, ACC.x); ACC.y = fmaf(AV.x, w0.y, ACC.y); \
            ACC.z = fmaf(AV.x, w0.z, ACC.z); ACC.w = fmaf(AV.x, w0.w, ACC.w); \
            ACC.x = fmaf(AV.y, w1.x, ACC.x); ACC.y = fmaf(AV.y, w1.y, ACC.y); \
            ACC.z = fmaf(AV.y, w1.z, ACC.z); ACC.w = fmaf(AV.y, w1.w, ACC.w); \
            ACC.x = fmaf(AV.z, w2.x, ACC.x); ACC.y = fmaf(AV.z, w2.y, ACC.y); \
            ACC.z = fmaf(AV.z, w2.z, ACC.z); ACC.w = fmaf(AV.z, w2.w, ACC.w); \
            ACC.x = fmaf(AV.w, w3.x, ACC.x); ACC.y = fmaf(AV.w, w3.y, ACC.y); \
            ACC.z = fmaf(AV.w, w3.z, ACC.z); ACC.w = fmaf(AV.w, w3.w, ACC.w);
            GSTEP(acc0, a0) GSTEP(acc1, a1) GSTEP(acc2, a2) GSTEP(acc3, a3)
        }
        if (Kd & 3) {
            const int rem = Kd & 3;
            const float4 z = make_float4(0.f,0.f,0.f,0.f);
            float4 w0 = (rem > 0) ? W4[(size_t)(kfull*4+0) * 75 + quad] : z;
            float4 w1 = (rem > 1) ? W4[(size_t)(kfull*4+1) * 75 + quad] : z;
            float4 w2 = (rem > 2) ? W4[(size_t)(kfull*4+2) * 75 + quad] : z;
            float4 w3 = z;
            float4 a0 = sa4[(r0+0) * Kd4 + kfull];
            float4 a1 = sa4[(r0+1) * Kd4 + kfull];
            float4 a2 = sa4[(r0+2) * Kd4 + kfull];
            float4 a3 = sa4[(r0+3) * Kd4 + kfull];
            GSTEP(acc0, a0) GSTEP(acc1, a1) GSTEP(acc2, a2) GSTEP(acc3, a3)
#undef GSTEP
        }

        const int col = widx * 300 + quad * 4;
        float4 bsv = make_float4(0.f,0.f,0.f,0.f);
        if (bias) bsv = ((const float4*)bias)[quad];
        float4 accs[4] = {acc0, acc1, acc2, acc3};
#pragma unroll
        for (int i = 0; i < 4; i++) {
            int row = row0 + r0 + i;
            if (row < M) {
                float4 v = accs[i];
                v.x += bsv.x; v.y += bsv.y; v.z += bsv.z; v.w += bsv.w;
                if (Add) {
                    float4 ad = *(const float4*)(Add + (size_t)row * ldAdd + addOff + quad * 4);
                    v.x += ad.x; v.y += ad.y; v.z += ad.z; v.w += ad.w;
                }
                if (act) {
                    v.x = fmaxf(v.x, 0.f); v.y = fmaxf(v.y, 0.f);
                    v.z = fmaxf(v.z, 0.f); v.w = fmaxf(v.w, 0.f);
                }
                *(float4*)(C + (size_t)row * ldc + col) = v;
            }
        }
    }
}

// ---------------------------------------------------------------------------
// k_neighbor v2: float4-vectorized, 4 bn per block, neighbor meta in LDS.
// Block dim (80,4): x = h-quad (75 active), y = bn within block.
// HW rows (f4 ld 300): [0:75)=WNA, [75:150)=U2a, [150:225)=self, [225:300)=U1a.
// FB rows (f4 ld 150): [0:75)=WNB, [75:150)=U2b.
// ---------------------------------------------------------------------------
__global__ __launch_bounds__(320) void k_neighbor(
    const float* __restrict__ HW, const float* __restrict__ FB,
    const int* __restrict__ atom_nb, const int* __restrict__ bond_nb,
    const float* __restrict__ mask_neis, const float* __restrict__ mask_atoms,
    const float* __restrict__ b_U2,
    float* __restrict__ local_out, float* __restrict__ nl_out)
{
    __shared__ int   sAn[4][MAXNB];
    __shared__ int   sBd[4][MAXNB];
    __shared__ float sM[4][MAXNB];
    const int tx = threadIdx.x;          // 0..79
    const int ty = threadIdx.y;          // 0..3
    const int bn0 = blockIdx.x * 4;
    const int flat = ty * 80 + tx;

    if (flat < 40)        sAn[flat / 10][flat % 10] = atom_nb[(bn0 + flat / 10) * MAXNB + flat % 10];
    else if (flat < 80)  { int f = flat - 40; sBd[f / 10][f % 10] = bond_nb[(bn0 + f / 10) * MAXNB + f % 10]; }
    else if (flat < 120) { int f = flat - 80; sM[f / 10][f % 10]  = mask_neis[(bn0 + f / 10) * MAXNB + f % 10]; }
    __syncthreads();

    if (tx >= 75) return;
    const int bn = bn0 + ty;
    const int b = bn / NN;
    const int h4 = tx;

    const float4* HW4 = (const float4*)HW;
    const float4* FB4 = (const float4*)FB;
    const float4 bu = ((const float4*)b_U2)[h4];

    float4 fnei = make_float4(0.f,0.f,0.f,0.f);
    float4 nls  = fnei;
#pragma unroll
    for (int k = 0; k < MAXNB; k++) {
        const int an = sAn[ty][k];
        const int bd = sBd[ty][k];
        const float m = sM[ty][k];
        const float4* hr = HW4 + (size_t)(b * NN + an) * 300;
        const float4* fr = FB4 + (size_t)(b * NBONDS + bd) * 150;
        float4 ha = hr[h4];
        float4 hu = hr[75 + h4];
        float4 fa = fr[h4];
        float4 fu = fr[75 + h4];
        fnei.x = fmaf(m, ha.x * fa.x, fnei.x);
        fnei.y = fmaf(m, ha.y * fa.y, fnei.y);
        fnei.z = fmaf(m, ha.z * fa.z, fnei.z);
        fnei.w = fmaf(m, ha.w * fa.w, fnei.w);
        float ux = hu.x + fu.x + bu.x;
        float uy = hu.y + fu.y + bu.y;
        float uz = hu.z + fu.z + bu.z;
        float uw = hu.w + fu.w + bu.w;
        nls.x = fmaf(m, fmaxf(ux, 0.f), nls.x);
        nls.y = fmaf(m, fmaxf(uy, 0.f), nls.y);
        nls.z = fmaf(m, fmaxf(uz, 0.f), nls.z);
        nls.w = fmaf(m, fmaxf(uw, 0.f), nls.w);
    }
    const float ma = mask_atoms[bn];
    const float4 sf = HW4[(size_t)bn * 300 + 150 + h4];
    float4 lo;
    lo.x = fnei.x * sf.x * ma;
    lo.y = fnei.y * sf.y * ma;
    lo.z = fnei.z * sf.z * ma;
    lo.w = fnei.w * sf.w * ma;
    ((float4*)local_out)[(size_t)bn * 75 + h4] = lo;
    ((float4*)nl_out)[(size_t)bn * 75 + h4]   = nls;
}

// ---------------------------------------------------------------------------
// k_pair v3 (MFMA): block = 16x16 pair tile for one batch, 256 threads.
// Binary term P[pair,h] = bin@Wbin computed via mfma_f32_16x16x32_bf16
// (K=11 padded to 32). Wave w owns i-rows 4w..4w+3 (groups), all 16 j, all h.
// u = P + (Ri+bvec) + Rj; s = sum_h relu(u)*Ws[h] (+bscore); sigmoid if mode 0.
// C/D layout: col=lane&15 (h), row=(lane>>4)*4+reg (j within tile).
// ---------------------------------------------------------------------------
__global__ __launch_bounds__(256) void k_pair(
    const float* __restrict__ R, int ldr,
    const float* __restrict__ binary_feats,
    const float* __restrict__ Wbin, const float* __restrict__ bvec,
    const float* __restrict__ Wscore, const float* __restrict__ bscore,
    float* __restrict__ outp, int mode)
{
    __shared__ float sLi[16 * 305];              // Ri + bvec (19.5 KB)
    __shared__ float sLj[16 * 305];              // Rj        (19.5 KB)
    __shared__ float sWs[304];                   // padded Wscore
    __shared__ unsigned short sWB[19 * 16 * 16]; // bf16 Wbin, frag layout (9.5 KB)

    const int i0 = blockIdx.x * 16;
    const int j0 = blockIdx.y * 16;
    const int b  = blockIdx.z;
    const int tid = threadIdx.x;
    const int lane = tid & 63;
    const int wid = tid >> 6;

    // ---- stage Li (+bvec) and Lj rows, zero-padded ----
    for (int idx = tid; idx < 16 * 305; idx += 256) {
        int r = idx / 305;
        int c = idx - r * 305;
        float vi = 0.f, vj = 0.f;
        if (c < 300) {
            if (i0 + r < NN) vi = R[(size_t)(b * NN + i0 + r) * ldr + c] + bvec[c];
            if (j0 + r < NN) vj = R[(size_t)(b * NN + j0 + r) * ldr + c];
        }
        sLi[idx] = vi;
        sLj[idx] = vj;
    }
    for (int idx = tid; idx < 304; idx += 256)
        sWs[idx] = (idx < 300) ? Wscore[idx] : 0.f;
    // ---- stage Wbin as bf16 in B-fragment layout: [(ch*16+n)*2+koct]*8+jj ----
    for (int idx = tid; idx < 19 * 256; idx += 256) {
        int ch = idx >> 8;
        int rem = idx & 255;
        int n = rem >> 4;
        int k = rem & 15;
        int h = ch * 16 + n;
        float f = (k < BIN && h < 300) ? Wbin[k * 300 + h] : 0.f;
        sWB[((ch * 16 + n) * 2 + (k >> 3)) * 8 + (k & 7)] = f2bf(f);
    }

    // ---- build A-fragments (bin rows; h-invariant) ----
    // A[m=lane&15][k=(lane>>4)*8+jj]; m = j within tile, group g -> i row wid*4+g
    const int m = lane & 15;
    const int koct = lane >> 4;
    short8 afrag[4];
#pragma unroll
    for (int g = 0; g < 4; g++) {
        const int li = wid * 4 + g;
        const bool v = (i0 + li < NN) && (j0 + m < NN);
        const float* bp = binary_feats +
            (size_t)((b * NN + (v ? i0 + li : 0)) * NN + (v ? j0 + m : 0)) * BIN;
        union { unsigned short u[8]; short8 s; } t;
#pragma unroll
        for (int jj = 0; jj < 8; jj++) {
            int k = koct * 8 + jj;
            float f = (v && k < BIN) ? bp[k] : 0.f;
            t.u[jj] = f2bf(f);
        }
        afrag[g] = t.s;
    }
    __syncthreads();

    const int n = lane & 15;
    const int rquad = lane >> 4;
    const floatx4 zero = {0.f, 0.f, 0.f, 0.f};
    float su[4][4];
#pragma unroll
    for (int g = 0; g < 4; g++)
#pragma unroll
        for (int r = 0; r < 4; r++) su[g][r] = 0.f;

    for (int ch = 0; ch < 19; ch++) {
        const int h0 = ch * 16;
        short8 bfrag = {0,0,0,0,0,0,0,0};
        if (lane < 32)
            bfrag = *(const short8*)&sWB[((ch * 16 + n) * 2 + koct) * 8];
        const float wsv = sWs[h0 + n];
#pragma unroll
        for (int g = 0; g < 4; g++) {
            floatx4 P = __builtin_amdgcn_mfma_f32_16x16x32_bf16(
                afrag[g], bfrag, zero, 0, 0, 0);
            const float liv = sLi[(wid * 4 + g) * 305 + h0 + n];
#pragma unroll
            for (int r = 0; r < 4; r++) {
                const float ljv = sLj[(rquad * 4 + r) * 305 + h0 + n];
                float u = P[r] + liv + ljv;
                su[g][r] = fmaf(fmaxf(u, 0.f), wsv, su[g][r]);
            }
        }
    }

    // ---- reduce over the 16 h-lanes (xor butterfly within 16-lane groups) ----
    const float bs = bscore[0];
#pragma unroll
    for (int g = 0; g < 4; g++) {
#pragma unroll
        for (int r = 0; r < 4; r++) {
            float v = su[g][r];
            v += __shfl_xor(v, 1);
            v += __shfl_xor(v, 2);
            v += __shfl_xor(v, 4);
            v += __shfl_xor(v, 8);
            if (n == 0) {
                const int i = i0 + wid * 4 + g;
                const int j = j0 + rquad * 4 + r;
                if (i < NN && j < NN) {
                    float s = v + bs;
                    outp[(size_t)(b * NN + i) * NN + j] =
                        (mode == 0) ? (1.f / (1.f + expf(-s))) : s;
                }
            }
        }
    }
}

// ---------------------------------------------------------------------------
// ctx[b,i,:] = sum_j att[b,i,j] * local[b,j,:]; 4 i-rows per block.
// ---------------------------------------------------------------------------
__global__ __launch_bounds__(320) void k_ctx(
    const float* __restrict__ att, const float* __restrict__ local,
    float* __restrict__ ctx)
{
    const int bx = blockIdx.x;           // b*25 + (i0/4)
    const int b = bx / 25;
    const int i0 = (bx % 25) * 4;
    const int tid = threadIdx.x;
    __shared__ float sa[4 * NN];
    for (int idx = tid; idx < 4 * NN; idx += 320) {
        int ii = idx / NN, j = idx - ii * NN;
        sa[idx] = att[(size_t)(b * NN + i0 + ii) * NN + j];
    }
    __syncthreads();
    if (tid < HH) {
        float acc0 = 0.f, acc1 = 0.f, acc2 = 0.f, acc3 = 0.f;
        for (int j = 0; j < NN; j++) {
            float lv = local[(size_t)(b * NN + j) * HH + tid];
            acc0 = fmaf(sa[j], lv, acc0);
            acc1 = fmaf(sa[NN + j], lv, acc1);
            acc2 = fmaf(sa[2 * NN + j], lv, acc2);
            acc3 = fmaf(sa[3 * NN + j], lv, acc3);
        }
        ctx[(size_t)(b * NN + i0 + 0) * HH + tid] = acc0;
        ctx[(size_t)(b * NN + i0 + 1) * HH + tid] = acc1;
        ctx[(size_t)(b * NN + i0 + 2) * HH + tid] = acc2;
        ctx[(size_t)(b * NN + i0 + 3) * HH + tid] = acc3;
    }
}

// ---------------------------------------------------------------------------
// Top-K v2: 1024 threads/block, per-wave histograms, wave-parallel suffix-scan.
// ---------------------------------------------------------------------------
__global__ __launch_bounds__(1024) void k_topk(
    const float* __restrict__ scores, float* __restrict__ topk_out)
{
    const int b = blockIdx.x;
    const int tid = threadIdx.x;
    const int wid = tid >> 6;
    const int lane = tid & 63;
    const float* sc = scores + (size_t)b * (NN * NN);

    __shared__ unsigned int skey[NN * NN];      // 40 KB
    __shared__ unsigned int whist[16 * 256];    // 16 KB
    __shared__ unsigned int hist[256];
    __shared__ unsigned int candU[KTOP];
    __shared__ int candI[KTOP];
    __shared__ int cntG;
    __shared__ int curMin;
    __shared__ unsigned int sh_pref, sh_mask;
    __shared__ int sh_kRem;
    __shared__ int sh_last;

    for (int idx = tid; idx < NN * NN; idx += 1024) {
        unsigned int u = __float_as_uint(sc[idx]);
        u = (u & 0x80000000u) ? ~u : (u | 0x80000000u);
        skey[idx] = u;
    }
    if (tid == 0) {
        sh_pref = 0u; sh_mask = 0u; sh_kRem = KTOP; cntG = 0; sh_last = -1;
    }
    __syncthreads();

    for (int pass = 0; pass < 4; pass++) {
        const int shift = 24 - 8 * pass;
        unsigned int* wh = whist + (wid << 8);
        wh[lane] = 0u; wh[lane + 64] = 0u; wh[lane + 128] = 0u; wh[lane + 192] = 0u;
        __syncthreads();
        const unsigned int pref = sh_pref, mask = sh_mask;
        for (int idx = tid; idx < NN * NN; idx += 1024) {
            unsigned int u = skey[idx];
            if ((u & mask) == pref)
                atomicAdd(&wh[(u >> shift) & 255u], 1u);
        }
        __syncthreads();
        if (tid < 256) {
            unsigned int s = 0u;
#pragma unroll
            for (int w = 0; w < 16; w++) s += whist[(w << 8) | tid];
            hist[tid] = s;
        }
        __syncthreads();
        if (wid == 0) {
            unsigned int h0 = hist[lane * 4 + 0];
            unsigned int h1 = hist[lane * 4 + 1];
            unsigned int h2 = hist[lane * 4 + 2];
            unsigned int h3 = hist[lane * 4 + 3];
            unsigned int own = h0 + h1 + h2 + h3;
            unsigned int suf = own;
#pragma unroll
            for (int off = 1; off < 64; off <<= 1) {
                unsigned int v = __shfl_down(suf, off);
                if (lane + off < 64) suf += v;
            }
            const int k = sh_kRem;
            const unsigned int above = suf - own;
            if (above < (unsigned int)k && suf >= (unsigned int)k) {
                unsigned int c = above, hb; int bsel;
                c += h3;
                if ((int)c >= k) { bsel = lane * 4 + 3; hb = h3; }
                else { c += h2;
                    if ((int)c >= k) { bsel = lane * 4 + 2; hb = h2; }
                    else { c += h1;
                        if ((int)c >= k) { bsel = lane * 4 + 1; hb = h1; }
                        else { c += h0; bsel = lane * 4; hb = h0; } } }
                sh_kRem = k - (int)(c - hb);
                sh_pref = pref | ((unsigned int)bsel << shift);
                sh_mask = mask | (0xFFu << shift);
            }
        }
        __syncthreads();
    }
    const unsigned int T = sh_pref;

    for (int idx = tid; idx < NN * NN; idx += 1024) {
        unsigned int u = skey[idx];
        if (u > T) {
            int pos = atomicAdd(&cntG, 1);
            candU[pos] = u;
            candI[pos] = idx;
        }
    }
    __syncthreads();
    const int needE = KTOP - cntG;

    for (int e = 0; e < needE; e++) {
        if (tid == 0) curMin = 0x7fffffff;
        __syncthreads();
        const int last = sh_last;
        for (int idx = tid; idx < NN * NN; idx += 1024) {
            if (skey[idx] == T && idx > last)
                atomicMin(&curMin, idx);
        }
        __syncthreads();
        if (tid == 0) {
            candU[cntG + e] = T;
            candI[cntG + e] = curMin;
            sh_last = curMin;
        }
        __syncthreads();
    }

    if (tid < KTOP) {
        const unsigned int mu = candU[tid];
        const int mi = candI[tid];
        int rank = 0;
        for (int o = 0; o < KTOP; o++) {
            unsigned int ou = candU[o];
            int oi = candI[o];
            if (ou > mu || (ou == mu && oi < mi)) rank++;
        }
        topk_out[b * KTOP + rank] = (float)mi;
    }
}

// ---------------------------------------------------------------------------
extern "C" void kernel_launch(void* const* d_in, const int* in_sizes, int n_in,
                              void* d_out, int out_size, void* d_ws, size_t ws_size,
                              hipStream_t stream) {
    const float* fatoms       = (const float*)d_in[0];
    const float* fbonds       = (const float*)d_in[1];
    const int*   atom_nb      = (const int*)d_in[2];
    const int*   bond_nb      = (const int*)d_in[3];
    const float* binary_feats = (const float*)d_in[6];
    const float* mask_neis    = (const float*)d_in[7];
    const float* mask_atoms   = (const float*)d_in[8];
    const float* W_atom       = (const float*)d_in[10];
    const float* W_nei_atom   = (const float*)d_in[11];
    const float* W_nei_bond   = (const float*)d_in[12];
    const float* W_self       = (const float*)d_in[13];
    const float* W_U2         = (const float*)d_in[14];
    const float* b_U2         = (const float*)d_in[15];
    const float* W_U1         = (const float*)d_in[16];
    const float* b_U1         = (const float*)d_in[17];
    const float* W_att_local  = (const float*)d_in[18];
    const float* W_att_bin    = (const float*)d_in[19];
    const float* b_att        = (const float*)d_in[20];
    const float* W_att_score  = (const float*)d_in[21];
    const float* b_att_score  = (const float*)d_in[22];
    const float* W_pl         = (const float*)d_in[23];
    const float* W_pg         = (const float*)d_in[24];
    const float* W_pb         = (const float*)d_in[25];
    const float* b_p          = (const float*)d_in[26];
    const float* W_out        = (const float*)d_in[27];
    const float* b_out        = (const float*)d_in[28];

    float* ws = (float*)d_ws;
    const int ROWS = BB * NN;            // 1600
    float* h     = ws;                                   // 1600*300
    float* HW    = h     + (size_t)ROWS * HH;            // 1600*1200
    float* FB    = HW    + (size_t)ROWS * 1200;          // 1920*600
    float* nl    = FB    + (size_t)BB * NBONDS * 600;    // 1600*300
    float* local = nl    + (size_t)ROWS * HH;            // 1600*300
    float* LL    = local + (size_t)ROWS * HH;            // 1600*600 [LW|LPL]
    float* ctx   = LL    + (size_t)ROWS * 600;           // 1600*300
    float* LPG   = ctx   + (size_t)ROWS * HH;            // 1600*300
    float* att   = LPG   + (size_t)ROWS * HH;            // 160000

    float* out = (float*)d_out;
    float* topk_out = out + (size_t)BB * NN * NN;

    // h = relu(fatoms @ W_atom)
    k_gemm300<<<dim3(1, 100), 320, 0, stream>>>(
        fatoms, ROWS, AF, W_atom, nullptr, nullptr, nullptr,
        h, HH, nullptr, nullptr, 0, 0, 1);

    // FB = fbonds @ [W_nei_bond | W_U2b]
    k_gemm300<<<dim3(2, 120), 320, 0, stream>>>(
        fbonds, BB * NBONDS, BF, W_nei_bond, W_U2 + 300 * 300, nullptr, nullptr,
        FB, 600, nullptr, nullptr, 0, 0, 0);

    for (int d = 0; d < DEPTH; d++) {
        int nW = (d == DEPTH - 1) ? 3 : 4;   // last depth: h-update unused
        // HW = h @ [W_nei_atom | W_U2a | W_self | W_U1a]
        k_gemm300<<<dim3(nW, 100), 320, 0, stream>>>(
            h, ROWS, HH, W_nei_atom, W_U2, W_self, W_U1,
            HW, 1200, nullptr, nullptr, 0, 0, 0);
        // gather + aggregate neighbors -> local, nl
        k_neighbor<<<dim3(ROWS / 4), dim3(80, 4), 0, stream>>>(
            HW, FB, atom_nb, bond_nb, mask_neis, mask_atoms, b_U2, local, nl);
        if (d < DEPTH - 1) {
            // h = relu(HW[:,900:1200] + nl @ W_U1b + b_U1)
            k_gemm300<<<dim3(1, 100), 320, 0, stream>>>(
                nl, ROWS, HH, W_U1 + 300 * 300, nullptr, nullptr, nullptr,
                h, HH, b_U1, HW, 1200, 900, 1);
        }
    }

    // LL = local @ [W_att_local | W_pl]
    k_gemm300<<<dim3(2, 100), 320, 0, stream>>>(
        local, ROWS, HH, W_att_local, W_pl, nullptr, nullptr,
        LL, 600, nullptr, nullptr, 0, 0, 0);

    // att[b,i,j] — MFMA pair kernel, mode 0 (sigmoid)
    k_pair<<<dim3(7, 7, BB), 256, 0, stream>>>(
        LL, 600, binary_feats, W_att_bin, b_att, W_att_score, b_att_score,
        att, 0);

    // ctx = att @ local (per batch), 4 rows/block
    k_ctx<<<dim3(BB * 25), 320, 0, stream>>>(att, local, ctx);

    // LPG = ctx @ W_pg + LPL
    k_gemm300<<<dim3(1, 100), 320, 0, stream>>>(
        ctx, ROWS, HH, W_pg, nullptr, nullptr, nullptr,
        LPG, HH, nullptr, LL, 600, 300, 0);

    // pair scores — MFMA pair kernel, mode 1 (linear)
    k_pair<<<dim3(7, 7, BB), 256, 0, stream>>>(
        LPG, 300, binary_feats, W_pb, b_p, W_out, b_out,
        out, 1);

    // top-k indices per batch (as float values)
    k_topk<<<dim3(BB), 1024, 0, stream>>>(out, topk_out);
}